// Round 1
// baseline (704.263 us; speedup 1.0000x reference)
//
#include <hip/hip_runtime.h>
#include <math.h>

// Problem constants (fixed by setup_inputs)
#define BB   8
#define NN   4096
#define DD   128
#define HH   4
#define CC   32
#define LLAY 3
#define DEG  16
#define NSEG (BB*NN)      // 32768
#define FF   512

// ---------------------------------------------------------------------------
// Tiled fp32 GEMM: C[M,N] = A[M,K] @ B[K,N] + bias[N]  (ACT=1 -> SiLU)
// Tile 64x64, KC=32, 256 threads (16x16), 4x4 microtile.
// M%64==0, N%64==0, K%32==0 guaranteed here.
// ---------------------------------------------------------------------------
template<int ACT>
__global__ __launch_bounds__(256) void gemm_kernel(
    const float* __restrict__ A, const float* __restrict__ B,
    const float* __restrict__ bias, float* __restrict__ C,
    int M, int N, int K)
{
    // As stored transposed [k][m], padded to 68 so float4 reads stay 16B-aligned
    __shared__ float As[32][68];
    __shared__ float Bs[32][64];

    const int tid = threadIdx.x;
    const int tx = tid & 15;        // 0..15  -> 4 cols each
    const int ty = tid >> 4;        // 0..15  -> 4 rows each
    const int bm = blockIdx.x * 64;
    const int bn = blockIdx.y * 64;

    float acc[4][4] = {};

    for (int k0 = 0; k0 < K; k0 += 32) {
        // A tile: 64 rows x 32 k -> transposed into As[k][m]; 512 float4, 2/thread
        #pragma unroll
        for (int i = 0; i < 2; ++i) {
            int idx  = tid + i * 256;         // float4 index 0..511
            int row  = idx >> 3;              // 8 float4 per row (32 floats)
            int col4 = idx & 7;
            float4 v = *(const float4*)(A + (size_t)(bm + row) * K + k0 + col4 * 4);
            As[col4*4+0][row] = v.x;
            As[col4*4+1][row] = v.y;
            As[col4*4+2][row] = v.z;
            As[col4*4+3][row] = v.w;
        }
        // B tile: 32 k x 64 n, row-major; 512 float4, 2/thread
        #pragma unroll
        for (int i = 0; i < 2; ++i) {
            int idx  = tid + i * 256;
            int row  = idx >> 4;              // 16 float4 per row (64 floats)
            int col4 = idx & 15;
            *(float4*)&Bs[row][col4*4] =
                *(const float4*)(B + (size_t)(k0 + row) * N + bn + col4 * 4);
        }
        __syncthreads();

        #pragma unroll
        for (int kk = 0; kk < 32; ++kk) {
            float a[4], b[4];
            *(float4*)a = *(const float4*)&As[kk][ty * 4];
            *(float4*)b = *(const float4*)&Bs[kk][tx * 4];
            #pragma unroll
            for (int i = 0; i < 4; ++i)
                #pragma unroll
                for (int j = 0; j < 4; ++j)
                    acc[i][j] = fmaf(a[i], b[j], acc[i][j]);
        }
        __syncthreads();
    }

    // epilogue: bias (+SiLU), float4 stores
    #pragma unroll
    for (int i = 0; i < 4; ++i) {
        int row = bm + ty * 4 + i;
        int col = bn + tx * 4;
        float4 v;
        float* vp = (float*)&v;
        #pragma unroll
        for (int j = 0; j < 4; ++j) {
            float t = acc[i][j] + bias[col + j];
            if (ACT == 1) t = t / (1.0f + __expf(-t));   // SiLU
            vp[j] = t;
        }
        *(float4*)(C + (size_t)row * N + col) = v;
    }
}

// ---------------------------------------------------------------------------
// GATv2 edge softmax + aggregate. One wave per target node.
// Exploits tgt = repeat(arange(B*N), DEG): node i owns edges [16i, 16i+16).
// Lane l handles channels (2l, 2l+1); head h = l>>4 (16 lanes per head).
// ---------------------------------------------------------------------------
__global__ __launch_bounds__(256) void gat_kernel(
    const float* __restrict__ gl, const float* __restrict__ gr,
    const int* __restrict__ src, const float* __restrict__ att,
    const float* __restrict__ bias, float* __restrict__ out)
{
    const int wave = threadIdx.x >> 6;
    const int lane = threadIdx.x & 63;
    const int node = blockIdx.x * 4 + wave;
    const int c0   = lane * 2;
    const int h    = lane >> 4;

    const float2 gri = *(const float2*)(gr + (size_t)node * DD + c0);
    const float a0 = att[h * CC + (c0 & 31)];
    const float a1 = att[h * CC + ((c0 + 1) & 31)];

    float glx[DEG], gly[DEG], logit[DEG];
    const int* sp = src + node * DEG;

    #pragma unroll
    for (int e = 0; e < DEG; ++e) {
        int s = sp[e];                                   // wave-uniform load
        float2 g = *(const float2*)(gl + (size_t)s * DD + c0);
        glx[e] = g.x; gly[e] = g.y;
        float v0 = g.x + gri.x; v0 = v0 > 0.0f ? v0 : 0.2f * v0;
        float v1 = g.y + gri.y; v1 = v1 > 0.0f ? v1 : 0.2f * v1;
        float p = v0 * a0 + v1 * a1;
        p += __shfl_xor(p, 1);
        p += __shfl_xor(p, 2);
        p += __shfl_xor(p, 4);
        p += __shfl_xor(p, 8);                           // per-head logit, all 16 lanes
        logit[e] = p;
    }

    float m = logit[0];
    #pragma unroll
    for (int e = 1; e < DEG; ++e) m = fmaxf(m, logit[e]);

    float den = 0.0f, accx = 0.0f, accy = 0.0f;
    #pragma unroll
    for (int e = 0; e < DEG; ++e) {
        float a = __expf(logit[e] - m);
        den += a;
        accx = fmaf(a, glx[e], accx);
        accy = fmaf(a, gly[e], accy);
    }
    float inv = 1.0f / den;
    float2 o;
    o.x = accx * inv + bias[c0];
    o.y = accy * inv + bias[c0 + 1];
    *(float2*)(out + (size_t)node * DD + c0) = o;
}

// ---------------------------------------------------------------------------
// LayerNorm over D=128. One wave per row; lane holds 2 channels.
// RES=1: normalizes (x + res). Writes gamma*xhat + beta.
// ---------------------------------------------------------------------------
template<int RES>
__global__ __launch_bounds__(256) void ln_kernel(
    const float* __restrict__ x, const float* __restrict__ res,
    const float* __restrict__ g, const float* __restrict__ b,
    float* __restrict__ out)
{
    const int wave = threadIdx.x >> 6;
    const int lane = threadIdx.x & 63;
    const int row  = blockIdx.x * 4 + wave;
    const int c0   = lane * 2;

    float2 v = *(const float2*)(x + (size_t)row * DD + c0);
    if (RES) {
        float2 r = *(const float2*)(res + (size_t)row * DD + c0);
        v.x += r.x; v.y += r.y;
    }
    float s = v.x + v.y;
    #pragma unroll
    for (int mk = 1; mk < 64; mk <<= 1) s += __shfl_xor(s, mk);
    const float mu = s * (1.0f / 128.0f);
    float dx = v.x - mu, dy = v.y - mu;
    float q = dx * dx + dy * dy;
    #pragma unroll
    for (int mk = 1; mk < 64; mk <<= 1) q += __shfl_xor(q, mk);
    const float rs = rsqrtf(q * (1.0f / 128.0f) + 1e-5f);

    float2 o;
    o.x = dx * rs * g[c0]     + b[c0];
    o.y = dy * rs * g[c0 + 1] + b[c0 + 1];
    *(float2*)(out + (size_t)row * DD + c0) = o;
}

// ---------------------------------------------------------------------------
extern "C" void kernel_launch(void* const* d_in, const int* in_sizes, int n_in,
                              void* d_out, int out_size, void* d_ws, size_t ws_size,
                              hipStream_t stream)
{
    const float* x        = (const float*)d_in[0];
    const float* lin_l_w  = (const float*)d_in[1];
    const float* lin_l_b  = (const float*)d_in[2];
    const float* lin_r_w  = (const float*)d_in[3];
    const float* lin_r_b  = (const float*)d_in[4];
    const float* att      = (const float*)d_in[5];
    const float* gat_bias = (const float*)d_in[6];
    const float* ln1_g    = (const float*)d_in[7];
    const float* ln1_b    = (const float*)d_in[8];
    const float* ff1_w    = (const float*)d_in[9];
    const float* ff1_b    = (const float*)d_in[10];
    const float* ff2_w    = (const float*)d_in[11];
    const float* ff2_b    = (const float*)d_in[12];
    const float* ln2_g    = (const float*)d_in[13];
    const float* ln2_b    = (const float*)d_in[14];
    const int*   src      = (const int*)d_in[15];     // edge_index row 0 (tgt row unused: tgt==repeat(arange))

    float* out = (float*)d_out;
    float* ws  = (float*)d_ws;

    // Workspace layout (floats): 4*4.19M + 16.78M = 33.55M floats = 134.2 MB
    const size_t NV = (size_t)NSEG * DD;              // 4,194,304
    float* XG  = ws;                                  // GAT output (residual source)
    float* B1  = XG + NV;                             // gl, then LN1 output
    float* B2  = B1 + NV;                             // gr, then FF2 output
    float* XN  = B2 + NV;                             // next-layer input
    float* HID = XN + NV;                             // FF hidden [32768,512]

    const float* xin = x;
    for (int l = 0; l < LLAY; ++l) {
        dim3 gLin(NSEG / 64, DD / 64);                // (512, 2)
        gemm_kernel<0><<<gLin, 256, 0, stream>>>(xin, lin_l_w + (size_t)l*DD*DD,
                                                 lin_l_b + l*DD, B1, NSEG, DD, DD);
        gemm_kernel<0><<<gLin, 256, 0, stream>>>(xin, lin_r_w + (size_t)l*DD*DD,
                                                 lin_r_b + l*DD, B2, NSEG, DD, DD);
        gat_kernel<<<NSEG / 4, 256, 0, stream>>>(B1, B2, src, att + l*HH*CC,
                                                 gat_bias + l*DD, XG);
        ln_kernel<0><<<NSEG / 4, 256, 0, stream>>>(XG, nullptr,
                                                   ln1_g + l*DD, ln1_b + l*DD, B1);
        dim3 gF1(NSEG / 64, FF / 64);                 // (512, 8)
        gemm_kernel<1><<<gF1, 256, 0, stream>>>(B1, ff1_w + (size_t)l*DD*FF,
                                                ff1_b + l*FF, HID, NSEG, FF, DD);
        gemm_kernel<0><<<gLin, 256, 0, stream>>>(HID, ff2_w + (size_t)l*FF*DD,
                                                 ff2_b + l*DD, B2, NSEG, DD, FF);
        float* xo = (l == LLAY - 1) ? out : XN;
        ln_kernel<1><<<NSEG / 4, 256, 0, stream>>>(XG, B2,
                                                   ln2_g + l*DD, ln2_b + l*DD, xo);
        xin = XN;
    }
}

// Round 7
// 483.201 us; speedup vs baseline: 1.4575x; 1.4575x over previous
//
#include <hip/hip_runtime.h>
#include <math.h>

// Problem constants (fixed by setup_inputs)
#define BB   8
#define NN   4096
#define DD   128
#define HH   4
#define CC   32
#define LLAY 3
#define DEG  16
#define NSEG (BB*NN)      // 32768
#define FF   512

typedef __bf16 bf16;
typedef __bf16 bf16x8 __attribute__((ext_vector_type(8)));
typedef float  f32x4  __attribute__((ext_vector_type(4)));

// ---------------------------------------------------------------------------
// fp32 tiled GEMM — used for lin_l / lin_r only.
// C[M,N] = A[M,K] @ B[K,N] + bias[N]
// ---------------------------------------------------------------------------
template<int ACT>
__global__ __launch_bounds__(256) void gemm_kernel(
    const float* __restrict__ A, const float* __restrict__ B,
    const float* __restrict__ bias, float* __restrict__ C,
    int M, int N, int K)
{
    __shared__ float As[32][68];
    __shared__ float Bs[32][64];

    const int tid = threadIdx.x;
    const int tx = tid & 15;
    const int ty = tid >> 4;
    const int bm = blockIdx.x * 64;
    const int bn = blockIdx.y * 64;

    float acc[4][4] = {};

    for (int k0 = 0; k0 < K; k0 += 32) {
        #pragma unroll
        for (int i = 0; i < 2; ++i) {
            int idx  = tid + i * 256;
            int row  = idx >> 3;
            int col4 = idx & 7;
            float4 v = *(const float4*)(A + (size_t)(bm + row) * K + k0 + col4 * 4);
            As[col4*4+0][row] = v.x;
            As[col4*4+1][row] = v.y;
            As[col4*4+2][row] = v.z;
            As[col4*4+3][row] = v.w;
        }
        #pragma unroll
        for (int i = 0; i < 2; ++i) {
            int idx  = tid + i * 256;
            int row  = idx >> 4;
            int col4 = idx & 15;
            *(float4*)&Bs[row][col4*4] =
                *(const float4*)(B + (size_t)(k0 + row) * N + bn + col4 * 4);
        }
        __syncthreads();

        #pragma unroll
        for (int kk = 0; kk < 32; ++kk) {
            float a[4], b[4];
            *(float4*)a = *(const float4*)&As[kk][ty * 4];
            *(float4*)b = *(const float4*)&Bs[kk][tx * 4];
            #pragma unroll
            for (int i = 0; i < 4; ++i)
                #pragma unroll
                for (int j = 0; j < 4; ++j)
                    acc[i][j] = fmaf(a[i], b[j], acc[i][j]);
        }
        __syncthreads();
    }

    #pragma unroll
    for (int i = 0; i < 4; ++i) {
        int row = bm + ty * 4 + i;
        int col = bn + tx * 4;
        float4 v;
        float* vp = (float*)&v;
        #pragma unroll
        for (int j = 0; j < 4; ++j) {
            float t = acc[i][j] + bias[col + j];
            if (ACT == 1) t = t / (1.0f + __expf(-t));
            vp[j] = t;
        }
        *(float4*)(C + (size_t)row * N + col) = v;
    }
}

// ---------------------------------------------------------------------------
// bf16 MFMA GEMM (m97 structure): C[M,N] = A[M,K] @ Bt[N,K]^T + bias
// 128x128 tile, BK=32, 4 waves (2x2), 4x4 frags of 16x16x32 per wave.
// global_load_lds width=16, linear LDS, 4-way XOR k-chunk swizzle
// (same involution on staging-source and frag-read sides).
// ACT=1 -> SiLU. OutT = __bf16 (FF1 hidden) or float (FF2 out).
// M%128==0, N%128==0, K%32==0.
// ---------------------------------------------------------------------------
template<int ACT, typename OutT>
__global__ __launch_bounds__(256) void mfma_gemm(
    const bf16* __restrict__ A, const bf16* __restrict__ Bt,
    const float* __restrict__ bias, OutT* __restrict__ C,
    int M, int N, int K)
{
    __shared__ bf16 As[128 * 32];
    __shared__ bf16 Bs[128 * 32];

    const int tid  = threadIdx.x;
    const int wave = tid >> 6;
    const int lane = tid & 63;
    const int wr   = wave >> 1;          // wave row 0..1 (64 M-rows each)
    const int wc   = wave & 1;           // wave col 0..1 (64 N-cols each)
    const int bm   = blockIdx.x * 128;
    const int bn   = blockIdx.y * 128;

    // frag-read addressing: row = l&15, k-chunk = l>>4, XOR-swizzled position
    const int lr   = lane & 15;
    const int lkp  = ((lane >> 4) ^ (lane & 3)) * 8;   // swizzled k position

    // staging addressing: lane i covers row i>>2 (of 16), k-chunk pos i&3;
    // position p holds data of original chunk p ^ (row&3)
    const int srow = lane >> 2;
    const int skb  = ((lane & 3) ^ ((lane >> 2) & 3)) * 8;

    f32x4 acc[4][4] = {};

    for (int k0 = 0; k0 < K; k0 += 32) {
        #pragma unroll
        for (int r = 0; r < 2; ++r) {
            int chunk = wave * 2 + r;                          // 0..7 (16 rows each)
            const bf16* ga = A + (size_t)(bm + chunk * 16 + srow) * K + k0 + skb;
            __builtin_amdgcn_global_load_lds(
                (const __attribute__((address_space(1))) void*)ga,
                (__attribute__((address_space(3))) void*)(As + chunk * 512),
                16, 0, 0);
            const bf16* gb = Bt + (size_t)(bn + chunk * 16 + srow) * K + k0 + skb;
            __builtin_amdgcn_global_load_lds(
                (const __attribute__((address_space(1))) void*)gb,
                (__attribute__((address_space(3))) void*)(Bs + chunk * 512),
                16, 0, 0);
        }
        __syncthreads();

        bf16x8 af[4], bfr[4];
        #pragma unroll
        for (int i = 0; i < 4; ++i)
            af[i] = *(const bf16x8*)&As[(wr * 64 + i * 16 + lr) * 32 + lkp];
        #pragma unroll
        for (int j = 0; j < 4; ++j)
            bfr[j] = *(const bf16x8*)&Bs[(wc * 64 + j * 16 + lr) * 32 + lkp];
        #pragma unroll
        for (int i = 0; i < 4; ++i)
            #pragma unroll
            for (int j = 0; j < 4; ++j)
                acc[i][j] = __builtin_amdgcn_mfma_f32_16x16x32_bf16(
                    af[i], bfr[j], acc[i][j], 0, 0, 0);
        __syncthreads();
    }

    // C/D layout (m89-verified): col = lane&15, row = (lane>>4)*4 + q
    const int orow = (lane >> 4) * 4;
    #pragma unroll
    for (int j = 0; j < 4; ++j) {
        int gcol = bn + wc * 64 + j * 16 + lr;
        float bv = bias[gcol];
        #pragma unroll
        for (int i = 0; i < 4; ++i) {
            int grow0 = bm + wr * 64 + i * 16 + orow;
            #pragma unroll
            for (int q = 0; q < 4; ++q) {
                float t = acc[i][j][q] + bv;
                if (ACT == 1) t = t / (1.0f + __expf(-t));   // SiLU
                C[(size_t)(grow0 + q) * N + gcol] = (OutT)t;
            }
        }
    }
}

// ---------------------------------------------------------------------------
// Weight transpose+convert: fp32 [K,N] -> bf16 [N,K] for all 3 layers of
// ff1_w (128x512) and ff2_w (512x128). 393216 total elements, one launch.
// ---------------------------------------------------------------------------
__global__ __launch_bounds__(256) void cvt_weights(
    const float* __restrict__ ff1_w, const float* __restrict__ ff2_w,
    bf16* __restrict__ wt1, bf16* __restrict__ wt2)
{
    int idx = blockIdx.x * 256 + threadIdx.x;      // 0 .. 393215
    if (idx < 196608) {
        int l = idx >> 16, e = idx & 65535;
        int k = e >> 9, n = e & 511;               // K=128, N=512
        wt1[l * 65536 + n * 128 + k] = (bf16)ff1_w[l * 65536 + k * 512 + n];
    } else {
        int r = idx - 196608;
        int l = r >> 16, e = r & 65535;
        int k = e >> 7, n = e & 127;               // K=512, N=128
        wt2[l * 65536 + n * 512 + k] = (bf16)ff2_w[l * 65536 + k * 128 + n];
    }
}

// ---------------------------------------------------------------------------
// Fused GATv2 edge softmax + aggregate + LayerNorm1. One wave per node.
// Exploits tgt = repeat(arange(B*N), DEG): node i owns edges [16i, 16i+16).
// Lane l handles channels (2l, 2l+1); head h = l>>4 (16 lanes per head).
// Writes XG (fp32, residual source) and LN1 output (bf16, FF1's A operand).
// ---------------------------------------------------------------------------
__global__ __launch_bounds__(256) void gat_ln_kernel(
    const float* __restrict__ gl, const float* __restrict__ gr,
    const int* __restrict__ src, const float* __restrict__ att,
    const float* __restrict__ bias,
    const float* __restrict__ ln_g, const float* __restrict__ ln_b,
    float* __restrict__ xg, bf16* __restrict__ ln_out)
{
    const int wave = threadIdx.x >> 6;
    const int lane = threadIdx.x & 63;
    const int node = blockIdx.x * 4 + wave;
    const int c0   = lane * 2;
    const int h    = lane >> 4;

    const float2 gri = *(const float2*)(gr + (size_t)node * DD + c0);
    const float a0 = att[h * CC + (c0 & 31)];
    const float a1 = att[h * CC + ((c0 + 1) & 31)];

    float glx[DEG], gly[DEG], logit[DEG];
    const int* sp = src + node * DEG;

    #pragma unroll
    for (int e = 0; e < DEG; ++e) {
        int s = sp[e];
        float2 g = *(const float2*)(gl + (size_t)s * DD + c0);
        glx[e] = g.x; gly[e] = g.y;
        float v0 = g.x + gri.x; v0 = v0 > 0.0f ? v0 : 0.2f * v0;
        float v1 = g.y + gri.y; v1 = v1 > 0.0f ? v1 : 0.2f * v1;
        float p = v0 * a0 + v1 * a1;
        p += __shfl_xor(p, 1);
        p += __shfl_xor(p, 2);
        p += __shfl_xor(p, 4);
        p += __shfl_xor(p, 8);
        logit[e] = p;
    }

    float m = logit[0];
    #pragma unroll
    for (int e = 1; e < DEG; ++e) m = fmaxf(m, logit[e]);

    float den = 0.0f, accx = 0.0f, accy = 0.0f;
    #pragma unroll
    for (int e = 0; e < DEG; ++e) {
        float a = __expf(logit[e] - m);
        den += a;
        accx = fmaf(a, glx[e], accx);
        accy = fmaf(a, gly[e], accy);
    }
    float inv = 1.0f / den;
    float2 o;
    o.x = accx * inv + bias[c0];
    o.y = accy * inv + bias[c0 + 1];
    *(float2*)(xg + (size_t)node * DD + c0) = o;

    // ---- fused LayerNorm over the 128 channels held by this wave ----
    float s = o.x + o.y;
    #pragma unroll
    for (int mk = 1; mk < 64; mk <<= 1) s += __shfl_xor(s, mk);
    const float mu = s * (1.0f / 128.0f);
    float dx = o.x - mu, dy = o.y - mu;
    float q = dx * dx + dy * dy;
    #pragma unroll
    for (int mk = 1; mk < 64; mk <<= 1) q += __shfl_xor(q, mk);
    const float rs = rsqrtf(q * (1.0f / 128.0f) + 1e-5f);

    ln_out[(size_t)node * DD + c0]     = (bf16)(dx * rs * ln_g[c0]     + ln_b[c0]);
    ln_out[(size_t)node * DD + c0 + 1] = (bf16)(dy * rs * ln_g[c0 + 1] + ln_b[c0 + 1]);
}

// ---------------------------------------------------------------------------
// LayerNorm over D=128 with residual: normalizes (x + res).
// One wave per row; lane holds 2 channels.
// ---------------------------------------------------------------------------
__global__ __launch_bounds__(256) void ln_res_kernel(
    const float* __restrict__ x, const float* __restrict__ res,
    const float* __restrict__ g, const float* __restrict__ b,
    float* __restrict__ out)
{
    const int wave = threadIdx.x >> 6;
    const int lane = threadIdx.x & 63;
    const int row  = blockIdx.x * 4 + wave;
    const int c0   = lane * 2;

    float2 v = *(const float2*)(x + (size_t)row * DD + c0);
    float2 r = *(const float2*)(res + (size_t)row * DD + c0);
    v.x += r.x; v.y += r.y;

    float s = v.x + v.y;
    #pragma unroll
    for (int mk = 1; mk < 64; mk <<= 1) s += __shfl_xor(s, mk);
    const float mu = s * (1.0f / 128.0f);
    float dx = v.x - mu, dy = v.y - mu;
    float q = dx * dx + dy * dy;
    #pragma unroll
    for (int mk = 1; mk < 64; mk <<= 1) q += __shfl_xor(q, mk);
    const float rs = rsqrtf(q * (1.0f / 128.0f) + 1e-5f);

    float2 o;
    o.x = dx * rs * g[c0]     + b[c0];
    o.y = dy * rs * g[c0 + 1] + b[c0 + 1];
    *(float2*)(out + (size_t)row * DD + c0) = o;
}

// ---------------------------------------------------------------------------
extern "C" void kernel_launch(void* const* d_in, const int* in_sizes, int n_in,
                              void* d_out, int out_size, void* d_ws, size_t ws_size,
                              hipStream_t stream)
{
    const float* x        = (const float*)d_in[0];
    const float* lin_l_w  = (const float*)d_in[1];
    const float* lin_l_b  = (const float*)d_in[2];
    const float* lin_r_w  = (const float*)d_in[3];
    const float* lin_r_b  = (const float*)d_in[4];
    const float* att      = (const float*)d_in[5];
    const float* gat_bias = (const float*)d_in[6];
    const float* ln1_g    = (const float*)d_in[7];
    const float* ln1_b    = (const float*)d_in[8];
    const float* ff1_w    = (const float*)d_in[9];
    const float* ff1_b    = (const float*)d_in[10];
    const float* ff2_w    = (const float*)d_in[11];
    const float* ff2_b    = (const float*)d_in[12];
    const float* ln2_g    = (const float*)d_in[13];
    const float* ln2_b    = (const float*)d_in[14];
    const int*   src      = (const int*)d_in[15];     // edge_index row 0

    float* out = (float*)d_out;
    float* ws  = (float*)d_ws;

    // Workspace layout: 5 fp32 node-bufs (16.78 MB ea) + bf16 LN1 (8.4 MB)
    // + bf16 hidden (33.6 MB) + bf16 weights (0.8 MB) = ~126.5 MB
    const size_t NV = (size_t)NSEG * DD;              // 4,194,304
    float* GL   = ws;                                 // lin_l output (fp32)
    float* GR   = GL + NV;                            // lin_r output (fp32)
    float* XG   = GR + NV;                            // GAT output (residual)
    float* FF2O = XG + NV;                            // FF2 output (fp32)
    float* XN   = FF2O + NV;                          // next-layer input
    bf16*  LN1B = (bf16*)(XN + NV);                   // LN1 output (bf16)
    bf16*  HID  = LN1B + NV;                          // FF hidden (bf16)
    bf16*  WT1  = HID + (size_t)NSEG * FF;            // ff1_w^T bf16 [L][512][128]
    bf16*  WT2  = WT1 + (size_t)LLAY * FF * DD;       // ff2_w^T bf16 [L][128][512]

    cvt_weights<<<1536, 256, 0, stream>>>(ff1_w, ff2_w, WT1, WT2);

    const float* xin = x;
    for (int l = 0; l < LLAY; ++l) {
        dim3 gLin(NSEG / 64, DD / 64);                // (512, 2)
        gemm_kernel<0><<<gLin, 256, 0, stream>>>(xin, lin_l_w + (size_t)l*DD*DD,
                                                 lin_l_b + l*DD, GL, NSEG, DD, DD);
        gemm_kernel<0><<<gLin, 256, 0, stream>>>(xin, lin_r_w + (size_t)l*DD*DD,
                                                 lin_r_b + l*DD, GR, NSEG, DD, DD);
        gat_ln_kernel<<<NSEG / 4, 256, 0, stream>>>(GL, GR, src, att + l*HH*CC,
                                                    gat_bias + l*DD,
                                                    ln1_g + l*DD, ln1_b + l*DD,
                                                    XG, LN1B);
        dim3 gF1(NSEG / 128, FF / 128);               // (256, 4)
        mfma_gemm<1, bf16><<<gF1, 256, 0, stream>>>(LN1B, WT1 + (size_t)l*FF*DD,
                                                    ff1_b + l*FF, HID, NSEG, FF, DD);
        dim3 gF2(NSEG / 128, DD / 128);               // (256, 1)
        mfma_gemm<0, float><<<gF2, 256, 0, stream>>>(HID, WT2 + (size_t)l*DD*FF,
                                                     ff2_b + l*DD, FF2O, NSEG, DD, FF);
        float* xo = (l == LLAY - 1) ? out : XN;
        ln_res_kernel<<<NSEG / 4, 256, 0, stream>>>(XG, FF2O,
                                                    ln2_g + l*DD, ln2_b + l*DD, xo);
        xin = XN;
    }
}

// Round 9
// 387.930 us; speedup vs baseline: 1.8154x; 1.2456x over previous
//
#include <hip/hip_runtime.h>
#include <math.h>

// Problem constants (fixed by setup_inputs)
#define BB   8
#define NN   4096
#define DD   128
#define HH   4
#define CC   32
#define LLAY 3
#define DEG  16
#define NSEG (BB*NN)      // 32768
#define FF   512

typedef __bf16 bf16;
typedef __bf16 bf16x4 __attribute__((ext_vector_type(4)));
typedef __bf16 bf16x8 __attribute__((ext_vector_type(8)));
typedef float  f32x4  __attribute__((ext_vector_type(4)));

// ---------------------------------------------------------------------------
// bf16 MFMA GEMM (m97 structure): C[M,N] = A[M,K] @ Bt[N,K]^T + bias
// 128x128 tile, BK=32, 4 waves (2x2), 4x4 frags of 16x16x32 per wave.
// global_load_lds width=16, linear LDS, 4-way XOR k-chunk swizzle
// (same involution on staging-source and frag-read sides).
// ACT=1 -> SiLU. OutT = __bf16 or float.  M%128==0, N%128==0, K%32==0.
// Used for: fused lin_l|lin_r (N=256), FF1 (N=512), FF2 (N=128, K=512).
// ---------------------------------------------------------------------------
template<int ACT, typename OutT>
__global__ __launch_bounds__(256) void mfma_gemm(
    const bf16* __restrict__ A, const bf16* __restrict__ Bt,
    const float* __restrict__ bias, OutT* __restrict__ C,
    int M, int N, int K)
{
    __shared__ bf16 As[128 * 32];
    __shared__ bf16 Bs[128 * 32];

    const int tid  = threadIdx.x;
    const int wave = tid >> 6;
    const int lane = tid & 63;
    const int wr   = wave >> 1;          // wave row 0..1 (64 M-rows each)
    const int wc   = wave & 1;           // wave col 0..1 (64 N-cols each)
    const int bm   = blockIdx.x * 128;
    const int bn   = blockIdx.y * 128;

    // frag-read addressing: row = l&15, k-chunk = l>>4, XOR-swizzled position
    const int lr   = lane & 15;
    const int lkp  = ((lane >> 4) ^ (lane & 3)) * 8;   // swizzled k position

    // staging addressing: lane i covers row i>>2 (of 16), k-chunk pos i&3;
    // position p holds data of original chunk p ^ (row&3)
    const int srow = lane >> 2;
    const int skb  = ((lane & 3) ^ ((lane >> 2) & 3)) * 8;

    f32x4 acc[4][4] = {};

    for (int k0 = 0; k0 < K; k0 += 32) {
        #pragma unroll
        for (int r = 0; r < 2; ++r) {
            int chunk = wave * 2 + r;                          // 0..7 (16 rows each)
            const bf16* ga = A + (size_t)(bm + chunk * 16 + srow) * K + k0 + skb;
            __builtin_amdgcn_global_load_lds(
                (const __attribute__((address_space(1))) void*)ga,
                (__attribute__((address_space(3))) void*)(As + chunk * 512),
                16, 0, 0);
            const bf16* gb = Bt + (size_t)(bn + chunk * 16 + srow) * K + k0 + skb;
            __builtin_amdgcn_global_load_lds(
                (const __attribute__((address_space(1))) void*)gb,
                (__attribute__((address_space(3))) void*)(Bs + chunk * 512),
                16, 0, 0);
        }
        __syncthreads();

        bf16x8 af[4], bfr[4];
        #pragma unroll
        for (int i = 0; i < 4; ++i)
            af[i] = *(const bf16x8*)&As[(wr * 64 + i * 16 + lr) * 32 + lkp];
        #pragma unroll
        for (int j = 0; j < 4; ++j)
            bfr[j] = *(const bf16x8*)&Bs[(wc * 64 + j * 16 + lr) * 32 + lkp];
        #pragma unroll
        for (int i = 0; i < 4; ++i)
            #pragma unroll
            for (int j = 0; j < 4; ++j)
                acc[i][j] = __builtin_amdgcn_mfma_f32_16x16x32_bf16(
                    af[i], bfr[j], acc[i][j], 0, 0, 0);
        __syncthreads();
    }

    // C/D layout (m89-verified): col = lane&15, row = (lane>>4)*4 + q
    const int orow = (lane >> 4) * 4;
    #pragma unroll
    for (int j = 0; j < 4; ++j) {
        int gcol = bn + wc * 64 + j * 16 + lr;
        float bv = bias[gcol];
        #pragma unroll
        for (int i = 0; i < 4; ++i) {
            int grow0 = bm + wr * 64 + i * 16 + orow;
            #pragma unroll
            for (int q = 0; q < 4; ++q) {
                float t = acc[i][j][q] + bv;
                if (ACT == 1) t = t / (1.0f + __expf(-t));   // SiLU
                C[(size_t)(grow0 + q) * N + gcol] = (OutT)t;
            }
        }
    }
}

// ---------------------------------------------------------------------------
// Weight transpose+convert (one launch, all layers):
//   WLR [L][256][128] bf16 : rows 0-127 = lin_l_w^T, 128-255 = lin_r_w^T
//   WT1 [L][512][128] bf16 : ff1_w^T
//   WT2 [L][128][512] bf16 : ff2_w^T
//   BLR [L][256] f32       : lin_l_b | lin_r_b
// ---------------------------------------------------------------------------
__global__ __launch_bounds__(256) void cvt_weights(
    const float* __restrict__ ll_w, const float* __restrict__ ll_b,
    const float* __restrict__ lr_w, const float* __restrict__ lr_b,
    const float* __restrict__ ff1_w, const float* __restrict__ ff2_w,
    bf16* __restrict__ wlr, bf16* __restrict__ wt1, bf16* __restrict__ wt2,
    float* __restrict__ blr)
{
    int idx = blockIdx.x * 256 + threadIdx.x;
    if (idx < 98304) {                             // WLR: 3*256*128
        int l = idx / 32768, e = idx % 32768;
        int n = e >> 7, k = e & 127;
        float v = (n < 128) ? ll_w[l * 16384 + k * 128 + n]
                            : lr_w[l * 16384 + k * 128 + (n - 128)];
        wlr[idx] = (bf16)v;
    } else if (idx < 294912) {                     // WT1: 3*128*512
        int r = idx - 98304;
        int l = r >> 16, e = r & 65535;
        int k = e >> 9, n = e & 511;
        wt1[l * 65536 + n * 128 + k] = (bf16)ff1_w[l * 65536 + k * 512 + n];
    } else if (idx < 491520) {                     // WT2: 3*512*128
        int r = idx - 294912;
        int l = r >> 16, e = r & 65535;
        int k = e >> 7, n = e & 127;
        wt2[l * 65536 + n * 512 + k] = (bf16)ff2_w[l * 65536 + k * 128 + n];
    } else if (idx < 492288) {                     // BLR: 3*256
        int r = idx - 491520;
        int l = r / 256, n = r % 256;
        blr[r] = (n < 128) ? ll_b[l * 128 + n] : lr_b[l * 128 + (n - 128)];
    }
}

// ---------------------------------------------------------------------------
// x fp32 -> bf16 (layer-0 lin input). 4 elems/thread.
// ---------------------------------------------------------------------------
__global__ __launch_bounds__(256) void cvt_x(
    const float* __restrict__ x, bf16* __restrict__ xb)
{
    int i = (blockIdx.x * 256 + threadIdx.x) * 4;
    float4 v = *(const float4*)(x + i);
    bf16x4 o = { (bf16)v.x, (bf16)v.y, (bf16)v.z, (bf16)v.w };
    *(bf16x4*)(xb + i) = o;
}

// ---------------------------------------------------------------------------
// Fused GATv2 edge softmax + aggregate + LayerNorm1. One wave per node.
// glr: [NSEG][256] fp32, cols 0-127 = gl, 128-255 = gr.
// Exploits tgt = repeat(arange(B*N), DEG): node i owns edges [16i, 16i+16).
// Lane l handles channels (2l, 2l+1); head h = l>>4 (16 lanes per head).
// Writes XG (fp32, residual source) and LN1 output (bf16, FF1's A operand).
// ---------------------------------------------------------------------------
__global__ __launch_bounds__(256) void gat_ln_kernel(
    const float* __restrict__ glr,
    const int* __restrict__ src, const float* __restrict__ att,
    const float* __restrict__ bias,
    const float* __restrict__ ln_g, const float* __restrict__ ln_b,
    float* __restrict__ xg, bf16* __restrict__ ln_out)
{
    const int wave = threadIdx.x >> 6;
    const int lane = threadIdx.x & 63;
    const int node = blockIdx.x * 4 + wave;
    const int c0   = lane * 2;
    const int h    = lane >> 4;

    const float2 gri = *(const float2*)(glr + (size_t)node * 256 + 128 + c0);
    const float a0 = att[h * CC + (c0 & 31)];
    const float a1 = att[h * CC + ((c0 + 1) & 31)];

    float glx[DEG], gly[DEG], logit[DEG];
    const int* sp = src + node * DEG;

    #pragma unroll
    for (int e = 0; e < DEG; ++e) {
        int s = sp[e];
        float2 g = *(const float2*)(glr + (size_t)s * 256 + c0);
        glx[e] = g.x; gly[e] = g.y;
        float v0 = g.x + gri.x; v0 = v0 > 0.0f ? v0 : 0.2f * v0;
        float v1 = g.y + gri.y; v1 = v1 > 0.0f ? v1 : 0.2f * v1;
        float p = v0 * a0 + v1 * a1;
        p += __shfl_xor(p, 1);
        p += __shfl_xor(p, 2);
        p += __shfl_xor(p, 4);
        p += __shfl_xor(p, 8);
        logit[e] = p;
    }

    float m = logit[0];
    #pragma unroll
    for (int e = 1; e < DEG; ++e) m = fmaxf(m, logit[e]);

    float den = 0.0f, accx = 0.0f, accy = 0.0f;
    #pragma unroll
    for (int e = 0; e < DEG; ++e) {
        float a = __expf(logit[e] - m);
        den += a;
        accx = fmaf(a, glx[e], accx);
        accy = fmaf(a, gly[e], accy);
    }
    float inv = 1.0f / den;
    float2 o;
    o.x = accx * inv + bias[c0];
    o.y = accy * inv + bias[c0 + 1];
    *(float2*)(xg + (size_t)node * DD + c0) = o;

    // ---- fused LayerNorm over the 128 channels held by this wave ----
    float s = o.x + o.y;
    #pragma unroll
    for (int mk = 1; mk < 64; mk <<= 1) s += __shfl_xor(s, mk);
    const float mu = s * (1.0f / 128.0f);
    float dx = o.x - mu, dy = o.y - mu;
    float q = dx * dx + dy * dy;
    #pragma unroll
    for (int mk = 1; mk < 64; mk <<= 1) q += __shfl_xor(q, mk);
    const float rs = rsqrtf(q * (1.0f / 128.0f) + 1e-5f);

    ln_out[(size_t)node * DD + c0]     = (bf16)(dx * rs * ln_g[c0]     + ln_b[c0]);
    ln_out[(size_t)node * DD + c0 + 1] = (bf16)(dy * rs * ln_g[c0 + 1] + ln_b[c0 + 1]);
}

// ---------------------------------------------------------------------------
// LayerNorm over D=128 with residual: normalizes (x + res).
// One wave per row; lane holds 2 channels. OutT: bf16 (next-layer lin input)
// or float (final output).
// ---------------------------------------------------------------------------
template<typename OutT>
__global__ __launch_bounds__(256) void ln_res_kernel(
    const float* __restrict__ x, const float* __restrict__ res,
    const float* __restrict__ g, const float* __restrict__ b,
    OutT* __restrict__ out)
{
    const int wave = threadIdx.x >> 6;
    const int lane = threadIdx.x & 63;
    const int row  = blockIdx.x * 4 + wave;
    const int c0   = lane * 2;

    float2 v = *(const float2*)(x + (size_t)row * DD + c0);
    float2 r = *(const float2*)(res + (size_t)row * DD + c0);
    v.x += r.x; v.y += r.y;

    float s = v.x + v.y;
    #pragma unroll
    for (int mk = 1; mk < 64; mk <<= 1) s += __shfl_xor(s, mk);
    const float mu = s * (1.0f / 128.0f);
    float dx = v.x - mu, dy = v.y - mu;
    float q = dx * dx + dy * dy;
    #pragma unroll
    for (int mk = 1; mk < 64; mk <<= 1) q += __shfl_xor(q, mk);
    const float rs = rsqrtf(q * (1.0f / 128.0f) + 1e-5f);

    out[(size_t)row * DD + c0]     = (OutT)(dx * rs * g[c0]     + b[c0]);
    out[(size_t)row * DD + c0 + 1] = (OutT)(dy * rs * g[c0 + 1] + b[c0 + 1]);
}

// ---------------------------------------------------------------------------
extern "C" void kernel_launch(void* const* d_in, const int* in_sizes, int n_in,
                              void* d_out, int out_size, void* d_ws, size_t ws_size,
                              hipStream_t stream)
{
    const float* x        = (const float*)d_in[0];
    const float* lin_l_w  = (const float*)d_in[1];
    const float* lin_l_b  = (const float*)d_in[2];
    const float* lin_r_w  = (const float*)d_in[3];
    const float* lin_r_b  = (const float*)d_in[4];
    const float* att      = (const float*)d_in[5];
    const float* gat_bias = (const float*)d_in[6];
    const float* ln1_g    = (const float*)d_in[7];
    const float* ln1_b    = (const float*)d_in[8];
    const float* ff1_w    = (const float*)d_in[9];
    const float* ff1_b    = (const float*)d_in[10];
    const float* ff2_w    = (const float*)d_in[11];
    const float* ff2_b    = (const float*)d_in[12];
    const float* ln2_g    = (const float*)d_in[13];
    const float* ln2_b    = (const float*)d_in[14];
    const int*   src      = (const int*)d_in[15];     // edge_index row 0

    float* out = (float*)d_out;
    float* ws  = (float*)d_ws;

    // Workspace layout (~118 MB):
    //   fp32: GLR [NSEG][256], XG [NSEG][128], FF2O [NSEG][128]
    //   bf16: XB [NSEG][128] (layer input), LN1B, HID [NSEG][512],
    //         WLR 3*256*128, WT1 3*512*128, WT2 3*128*512
    //   fp32: BLR 3*256
    const size_t NV = (size_t)NSEG * DD;              // 4,194,304
    float* GLR  = ws;                                 // fused lin out (stride 256)
    float* XG   = GLR + 2 * NV;                       // GAT out (residual)
    float* FF2O = XG + NV;                            // FF2 out
    bf16*  XB   = (bf16*)(FF2O + NV);                 // lin input (bf16)
    bf16*  LN1B = XB + NV;                            // LN1 out (bf16)
    bf16*  HID  = LN1B + NV;                          // FF hidden (bf16)
    bf16*  WLR  = HID + (size_t)NSEG * FF;            // lin weights^T cat
    bf16*  WT1  = WLR + (size_t)LLAY * 256 * DD;
    bf16*  WT2  = WT1 + (size_t)LLAY * FF * DD;
    float* BLR  = (float*)(WT2 + (size_t)LLAY * DD * FF);

    cvt_weights<<<1923, 256, 0, stream>>>(lin_l_w, lin_l_b, lin_r_w, lin_r_b,
                                          ff1_w, ff2_w, WLR, WT1, WT2, BLR);
    cvt_x<<<4096, 256, 0, stream>>>(x, XB);

    for (int l = 0; l < LLAY; ++l) {
        dim3 gLin(NSEG / 128, 256 / 128);             // (256, 2)
        mfma_gemm<0, float><<<gLin, 256, 0, stream>>>(XB, WLR + (size_t)l*256*DD,
                                                      BLR + l*256, GLR, NSEG, 256, DD);
        gat_ln_kernel<<<NSEG / 4, 256, 0, stream>>>(GLR, src, att + l*HH*CC,
                                                    gat_bias + l*DD,
                                                    ln1_g + l*DD, ln1_b + l*DD,
                                                    XG, LN1B);
        dim3 gF1(NSEG / 128, FF / 128);               // (256, 4)
        mfma_gemm<1, bf16><<<gF1, 256, 0, stream>>>(LN1B, WT1 + (size_t)l*FF*DD,
                                                    ff1_b + l*FF, HID, NSEG, FF, DD);
        dim3 gF2(NSEG / 128, DD / 128);               // (256, 1)
        mfma_gemm<0, float><<<gF2, 256, 0, stream>>>(HID, WT2 + (size_t)l*DD*FF,
                                                     ff2_b + l*DD, FF2O, NSEG, DD, FF);
        if (l == LLAY - 1) {
            ln_res_kernel<float><<<NSEG / 4, 256, 0, stream>>>(
                XG, FF2O, ln2_g + l*DD, ln2_b + l*DD, out);
        } else {
            ln_res_kernel<bf16><<<NSEG / 4, 256, 0, stream>>>(
                XG, FF2O, ln2_g + l*DD, ln2_b + l*DD, XB);
        }
    }
}

// Round 10
// 381.347 us; speedup vs baseline: 1.8468x; 1.0173x over previous
//
#include <hip/hip_runtime.h>
#include <math.h>

// Problem constants (fixed by setup_inputs)
#define BB   8
#define NN   4096
#define DD   128
#define HH   4
#define CC   32
#define LLAY 3
#define DEG  16
#define NSEG (BB*NN)      // 32768
#define FF   512

typedef __bf16 bf16;
typedef __bf16 bf16x4 __attribute__((ext_vector_type(4)));
typedef __bf16 bf16x8 __attribute__((ext_vector_type(8)));
typedef float  f32x4  __attribute__((ext_vector_type(4)));

// ---------------------------------------------------------------------------
// bf16 MFMA GEMM (m97 structure): C[M,N] = A[M,K] @ Bt[N,K]^T + bias
// 128x128 tile, BK=32, 4 waves (2x2), 4x4 frags of 16x16x32 per wave.
// global_load_lds width=16, linear LDS, 4-way XOR k-chunk swizzle
// (same involution on staging-source and frag-read sides).
// ACT=1 -> SiLU. OutT = __bf16 or float.  M%128==0, N%128==0, K%32==0.
// Used for: fused lin_l|lin_r (N=256), FF1 (N=512), FF2 (N=128, K=512).
// ---------------------------------------------------------------------------
template<int ACT, typename OutT>
__global__ __launch_bounds__(256) void mfma_gemm(
    const bf16* __restrict__ A, const bf16* __restrict__ Bt,
    const float* __restrict__ bias, OutT* __restrict__ C,
    int M, int N, int K)
{
    __shared__ bf16 As[128 * 32];
    __shared__ bf16 Bs[128 * 32];

    const int tid  = threadIdx.x;
    const int wave = tid >> 6;
    const int lane = tid & 63;
    const int wr   = wave >> 1;          // wave row 0..1 (64 M-rows each)
    const int wc   = wave & 1;           // wave col 0..1 (64 N-cols each)
    const int bm   = blockIdx.x * 128;
    const int bn   = blockIdx.y * 128;

    // frag-read addressing: row = l&15, k-chunk = l>>4, XOR-swizzled position
    const int lr   = lane & 15;
    const int lkp  = ((lane >> 4) ^ (lane & 3)) * 8;   // swizzled k position

    // staging addressing: lane i covers row i>>2 (of 16), k-chunk pos i&3;
    // position p holds data of original chunk p ^ (row&3)
    const int srow = lane >> 2;
    const int skb  = ((lane & 3) ^ ((lane >> 2) & 3)) * 8;

    f32x4 acc[4][4] = {};

    for (int k0 = 0; k0 < K; k0 += 32) {
        #pragma unroll
        for (int r = 0; r < 2; ++r) {
            int chunk = wave * 2 + r;                          // 0..7 (16 rows each)
            const bf16* ga = A + (size_t)(bm + chunk * 16 + srow) * K + k0 + skb;
            __builtin_amdgcn_global_load_lds(
                (const __attribute__((address_space(1))) void*)ga,
                (__attribute__((address_space(3))) void*)(As + chunk * 512),
                16, 0, 0);
            const bf16* gb = Bt + (size_t)(bn + chunk * 16 + srow) * K + k0 + skb;
            __builtin_amdgcn_global_load_lds(
                (const __attribute__((address_space(1))) void*)gb,
                (__attribute__((address_space(3))) void*)(Bs + chunk * 512),
                16, 0, 0);
        }
        __syncthreads();

        bf16x8 af[4], bfr[4];
        #pragma unroll
        for (int i = 0; i < 4; ++i)
            af[i] = *(const bf16x8*)&As[(wr * 64 + i * 16 + lr) * 32 + lkp];
        #pragma unroll
        for (int j = 0; j < 4; ++j)
            bfr[j] = *(const bf16x8*)&Bs[(wc * 64 + j * 16 + lr) * 32 + lkp];
        #pragma unroll
        for (int i = 0; i < 4; ++i)
            #pragma unroll
            for (int j = 0; j < 4; ++j)
                acc[i][j] = __builtin_amdgcn_mfma_f32_16x16x32_bf16(
                    af[i], bfr[j], acc[i][j], 0, 0, 0);
        __syncthreads();
    }

    // C/D layout (m89-verified): col = lane&15, row = (lane>>4)*4 + q
    const int orow = (lane >> 4) * 4;
    #pragma unroll
    for (int j = 0; j < 4; ++j) {
        int gcol = bn + wc * 64 + j * 16 + lr;
        float bv = bias[gcol];
        #pragma unroll
        for (int i = 0; i < 4; ++i) {
            int grow0 = bm + wr * 64 + i * 16 + orow;
            #pragma unroll
            for (int q = 0; q < 4; ++q) {
                float t = acc[i][j][q] + bv;
                if (ACT == 1) t = t / (1.0f + __expf(-t));   // SiLU
                C[(size_t)(grow0 + q) * N + gcol] = (OutT)t;
            }
        }
    }
}

// ---------------------------------------------------------------------------
// Weight transpose+convert (one launch, all layers):
//   WLR [L][256][128] bf16 : rows 0-127 = lin_l_w^T, 128-255 = lin_r_w^T
//   WT1 [L][512][128] bf16 : ff1_w^T
//   WT2 [L][128][512] bf16 : ff2_w^T
//   BLR [L][256] f32       : lin_l_b | lin_r_b
// ---------------------------------------------------------------------------
__global__ __launch_bounds__(256) void cvt_weights(
    const float* __restrict__ ll_w, const float* __restrict__ ll_b,
    const float* __restrict__ lr_w, const float* __restrict__ lr_b,
    const float* __restrict__ ff1_w, const float* __restrict__ ff2_w,
    bf16* __restrict__ wlr, bf16* __restrict__ wt1, bf16* __restrict__ wt2,
    float* __restrict__ blr)
{
    int idx = blockIdx.x * 256 + threadIdx.x;
    if (idx < 98304) {                             // WLR: 3*256*128
        int l = idx / 32768, e = idx % 32768;
        int n = e >> 7, k = e & 127;
        float v = (n < 128) ? ll_w[l * 16384 + k * 128 + n]
                            : lr_w[l * 16384 + k * 128 + (n - 128)];
        wlr[idx] = (bf16)v;
    } else if (idx < 294912) {                     // WT1: 3*128*512
        int r = idx - 98304;
        int l = r >> 16, e = r & 65535;
        int k = e >> 9, n = e & 511;
        wt1[l * 65536 + n * 128 + k] = (bf16)ff1_w[l * 65536 + k * 512 + n];
    } else if (idx < 491520) {                     // WT2: 3*512*128
        int r = idx - 294912;
        int l = r >> 16, e = r & 65535;
        int k = e >> 7, n = e & 127;
        wt2[l * 65536 + n * 512 + k] = (bf16)ff2_w[l * 65536 + k * 128 + n];
    } else if (idx < 492288) {                     // BLR: 3*256
        int r = idx - 491520;
        int l = r / 256, n = r % 256;
        blr[r] = (n < 128) ? ll_b[l * 128 + n] : lr_b[l * 128 + (n - 128)];
    }
}

// ---------------------------------------------------------------------------
// x fp32 -> bf16 (layer-0 lin input). 4 elems/thread.
// ---------------------------------------------------------------------------
__global__ __launch_bounds__(256) void cvt_x(
    const float* __restrict__ x, bf16* __restrict__ xb)
{
    int i = (blockIdx.x * 256 + threadIdx.x) * 4;
    float4 v = *(const float4*)(x + i);
    bf16x4 o = { (bf16)v.x, (bf16)v.y, (bf16)v.z, (bf16)v.w };
    *(bf16x4*)(xb + i) = o;
}

// ---------------------------------------------------------------------------
// Fused GATv2 edge softmax + aggregate + LayerNorm1. One wave per node.
// glr: [NSEG][256] fp32, cols 0-127 = gl, 128-255 = gr.
// Exploits tgt = repeat(arange(B*N), DEG): node i owns edges [16i, 16i+16).
// Lane l handles channels (2l, 2l+1); head h = l>>4 (16 lanes per head).
// Writes XG (fp32, residual source) and LN1 output (bf16, FF1's A operand).
//
// XCD-aware swizzle (T1): the gather glr[src] stays within one batch block
// (2 MB gl working set). 8192 blocks round-robin across 8 XCDs by blockIdx%8,
// so map bid -> (bid&7)*1024 + (bid>>3): all 1024 blocks of batch block b
// carry bid%8==b and land on one XCD whose 4 MB L2 holds that batch's slice.
// Bijective (8192 = 8*1024). Zero numerics impact.
// ---------------------------------------------------------------------------
__global__ __launch_bounds__(256) void gat_ln_kernel(
    const float* __restrict__ glr,
    const int* __restrict__ src, const float* __restrict__ att,
    const float* __restrict__ bias,
    const float* __restrict__ ln_g, const float* __restrict__ ln_b,
    float* __restrict__ xg, bf16* __restrict__ ln_out)
{
    const int wave = threadIdx.x >> 6;
    const int lane = threadIdx.x & 63;
    const int bid  = blockIdx.x;
    const int sb   = ((bid & 7) << 10) | (bid >> 3);   // XCD-chunked remap
    const int node = sb * 4 + wave;
    const int c0   = lane * 2;
    const int h    = lane >> 4;

    const float2 gri = *(const float2*)(glr + (size_t)node * 256 + 128 + c0);
    const float a0 = att[h * CC + (c0 & 31)];
    const float a1 = att[h * CC + ((c0 + 1) & 31)];

    float glx[DEG], gly[DEG], logit[DEG];
    const int* sp = src + node * DEG;

    #pragma unroll
    for (int e = 0; e < DEG; ++e) {
        int s = sp[e];
        float2 g = *(const float2*)(glr + (size_t)s * 256 + c0);
        glx[e] = g.x; gly[e] = g.y;
        float v0 = g.x + gri.x; v0 = v0 > 0.0f ? v0 : 0.2f * v0;
        float v1 = g.y + gri.y; v1 = v1 > 0.0f ? v1 : 0.2f * v1;
        float p = v0 * a0 + v1 * a1;
        p += __shfl_xor(p, 1);
        p += __shfl_xor(p, 2);
        p += __shfl_xor(p, 4);
        p += __shfl_xor(p, 8);
        logit[e] = p;
    }

    float m = logit[0];
    #pragma unroll
    for (int e = 1; e < DEG; ++e) m = fmaxf(m, logit[e]);

    float den = 0.0f, accx = 0.0f, accy = 0.0f;
    #pragma unroll
    for (int e = 0; e < DEG; ++e) {
        float a = __expf(logit[e] - m);
        den += a;
        accx = fmaf(a, glx[e], accx);
        accy = fmaf(a, gly[e], accy);
    }
    float inv = 1.0f / den;
    float2 o;
    o.x = accx * inv + bias[c0];
    o.y = accy * inv + bias[c0 + 1];
    *(float2*)(xg + (size_t)node * DD + c0) = o;

    // ---- fused LayerNorm over the 128 channels held by this wave ----
    float s = o.x + o.y;
    #pragma unroll
    for (int mk = 1; mk < 64; mk <<= 1) s += __shfl_xor(s, mk);
    const float mu = s * (1.0f / 128.0f);
    float dx = o.x - mu, dy = o.y - mu;
    float q = dx * dx + dy * dy;
    #pragma unroll
    for (int mk = 1; mk < 64; mk <<= 1) q += __shfl_xor(q, mk);
    const float rs = rsqrtf(q * (1.0f / 128.0f) + 1e-5f);

    ln_out[(size_t)node * DD + c0]     = (bf16)(dx * rs * ln_g[c0]     + ln_b[c0]);
    ln_out[(size_t)node * DD + c0 + 1] = (bf16)(dy * rs * ln_g[c0 + 1] + ln_b[c0 + 1]);
}

// ---------------------------------------------------------------------------
// LayerNorm over D=128 with residual: normalizes (x + res).
// One wave per row; lane holds 2 channels. OutT: bf16 (next-layer lin input)
// or float (final output).
// ---------------------------------------------------------------------------
template<typename OutT>
__global__ __launch_bounds__(256) void ln_res_kernel(
    const float* __restrict__ x, const float* __restrict__ res,
    const float* __restrict__ g, const float* __restrict__ b,
    OutT* __restrict__ out)
{
    const int wave = threadIdx.x >> 6;
    const int lane = threadIdx.x & 63;
    const int row  = blockIdx.x * 4 + wave;
    const int c0   = lane * 2;

    float2 v = *(const float2*)(x + (size_t)row * DD + c0);
    float2 r = *(const float2*)(res + (size_t)row * DD + c0);
    v.x += r.x; v.y += r.y;

    float s = v.x + v.y;
    #pragma unroll
    for (int mk = 1; mk < 64; mk <<= 1) s += __shfl_xor(s, mk);
    const float mu = s * (1.0f / 128.0f);
    float dx = v.x - mu, dy = v.y - mu;
    float q = dx * dx + dy * dy;
    #pragma unroll
    for (int mk = 1; mk < 64; mk <<= 1) q += __shfl_xor(q, mk);
    const float rs = rsqrtf(q * (1.0f / 128.0f) + 1e-5f);

    out[(size_t)row * DD + c0]     = (OutT)(dx * rs * g[c0]     + b[c0]);
    out[(size_t)row * DD + c0 + 1] = (OutT)(dy * rs * g[c0 + 1] + b[c0 + 1]);
}

// ---------------------------------------------------------------------------
extern "C" void kernel_launch(void* const* d_in, const int* in_sizes, int n_in,
                              void* d_out, int out_size, void* d_ws, size_t ws_size,
                              hipStream_t stream)
{
    const float* x        = (const float*)d_in[0];
    const float* lin_l_w  = (const float*)d_in[1];
    const float* lin_l_b  = (const float*)d_in[2];
    const float* lin_r_w  = (const float*)d_in[3];
    const float* lin_r_b  = (const float*)d_in[4];
    const float* att      = (const float*)d_in[5];
    const float* gat_bias = (const float*)d_in[6];
    const float* ln1_g    = (const float*)d_in[7];
    const float* ln1_b    = (const float*)d_in[8];
    const float* ff1_w    = (const float*)d_in[9];
    const float* ff1_b    = (const float*)d_in[10];
    const float* ff2_w    = (const float*)d_in[11];
    const float* ff2_b    = (const float*)d_in[12];
    const float* ln2_g    = (const float*)d_in[13];
    const float* ln2_b    = (const float*)d_in[14];
    const int*   src      = (const int*)d_in[15];     // edge_index row 0

    float* out = (float*)d_out;
    float* ws  = (float*)d_ws;

    // Workspace layout (~118 MB):
    //   fp32: GLR [NSEG][256], XG [NSEG][128], FF2O [NSEG][128]
    //   bf16: XB [NSEG][128] (layer input), LN1B, HID [NSEG][512],
    //         WLR 3*256*128, WT1 3*512*128, WT2 3*128*512
    //   fp32: BLR 3*256
    const size_t NV = (size_t)NSEG * DD;              // 4,194,304
    float* GLR  = ws;                                 // fused lin out (stride 256)
    float* XG   = GLR + 2 * NV;                       // GAT out (residual)
    float* FF2O = XG + NV;                            // FF2 out
    bf16*  XB   = (bf16*)(FF2O + NV);                 // lin input (bf16)
    bf16*  LN1B = XB + NV;                            // LN1 out (bf16)
    bf16*  HID  = LN1B + NV;                          // FF hidden (bf16)
    bf16*  WLR  = HID + (size_t)NSEG * FF;            // lin weights^T cat
    bf16*  WT1  = WLR + (size_t)LLAY * 256 * DD;
    bf16*  WT2  = WT1 + (size_t)LLAY * FF * DD;
    float* BLR  = (float*)(WT2 + (size_t)LLAY * DD * FF);

    cvt_weights<<<1923, 256, 0, stream>>>(lin_l_w, lin_l_b, lin_r_w, lin_r_b,
                                          ff1_w, ff2_w, WLR, WT1, WT2, BLR);
    cvt_x<<<4096, 256, 0, stream>>>(x, XB);

    for (int l = 0; l < LLAY; ++l) {
        dim3 gLin(NSEG / 128, 256 / 128);             // (256, 2)
        mfma_gemm<0, float><<<gLin, 256, 0, stream>>>(XB, WLR + (size_t)l*256*DD,
                                                      BLR + l*256, GLR, NSEG, 256, DD);
        gat_ln_kernel<<<NSEG / 4, 256, 0, stream>>>(GLR, src, att + l*HH*CC,
                                                    gat_bias + l*DD,
                                                    ln1_g + l*DD, ln1_b + l*DD,
                                                    XG, LN1B);
        dim3 gF1(NSEG / 128, FF / 128);               // (256, 4)
        mfma_gemm<1, bf16><<<gF1, 256, 0, stream>>>(LN1B, WT1 + (size_t)l*FF*DD,
                                                    ff1_b + l*FF, HID, NSEG, FF, DD);
        dim3 gF2(NSEG / 128, DD / 128);               // (256, 1)
        mfma_gemm<0, float><<<gF2, 256, 0, stream>>>(HID, WT2 + (size_t)l*DD*FF,
                                                     ff2_b + l*DD, FF2O, NSEG, DD, FF);
        if (l == LLAY - 1) {
            ln_res_kernel<float><<<NSEG / 4, 256, 0, stream>>>(
                XG, FF2O, ln2_g + l*DD, ln2_b + l*DD, out);
        } else {
            ln_res_kernel<bf16><<<NSEG / 4, 256, 0, stream>>>(
                XG, FF2O, ln2_g + l*DD, ln2_b + l*DD, XB);
        }
    }
}